// Round 13
// baseline (85.394 us; speedup 1.0000x reference)
//
#include <hip/hip_runtime.h>
#include <math.h>

#define BB   64      // batch
#define TT   512     // time
#define NCH  7       // channels
#define SS   4       // scales
#define MM   100000  // memory entries
#define DD   64      // embed dim
#define PRED 96      // pred_len
#define NBLK 512     // k2 blocks per scale (r13: 256->512, occupancy 4->8 blk/CU)
#define KPB  196     // ceil(MM/NBLK); 512*196=100352 >= MM
#define KLSH 72      // f16 plane row stride (shorts): 144B rows -> 16B-aligned b128 frags

typedef __attribute__((ext_vector_type(8))) _Float16 f16x8;
typedef __attribute__((ext_vector_type(4))) _Float16 f16x4;
typedef __attribute__((ext_vector_type(4))) float    f32x4;

// ---------------- wave reductions ----------------
__device__ __forceinline__ float wsum(float v){
  v += __shfl_xor(v,32); v += __shfl_xor(v,16); v += __shfl_xor(v,8);
  v += __shfl_xor(v,4);  v += __shfl_xor(v,2);  v += __shfl_xor(v,1);
  return v;
}
__device__ __forceinline__ float wmaxall(float v){
  v = fmaxf(v,__shfl_xor(v,32)); v = fmaxf(v,__shfl_xor(v,16));
  v = fmaxf(v,__shfl_xor(v,8));  v = fmaxf(v,__shfl_xor(v,4));
  v = fmaxf(v,__shfl_xor(v,2));  v = fmaxf(v,__shfl_xor(v,1));
  return v;
}
__device__ __forceinline__ float wminall(float v){
  v = fminf(v,__shfl_xor(v,32)); v = fminf(v,__shfl_xor(v,16));
  v = fminf(v,__shfl_xor(v,8));  v = fminf(v,__shfl_xor(v,4));
  v = fminf(v,__shfl_xor(v,2));  v = fminf(v,__shfl_xor(v,1));
  return v;
}

__device__ __forceinline__ float log_marg(float n, float mean, float var,
                                          float pm, float pv, float nv){
  float post_var = 1.f/(1.f/pv + n/nv);
  float post_mean = post_var*(pm/pv + n*mean/nv);
  return -0.5f*n*logf(6.283185307179586f*nv)
       + 0.5f*logf(post_var/pv)
       - 0.5f*(n*var/nv + mean*mean*n/nv - post_mean*post_mean/post_var + pm*pm/pv);
}

// sorted-desc top5 insert on registers tv0..tv4 / ti0..ti4
#define TOP5_INSERT(v, ii) \
  if ((v) > tv4) { \
    if ((v) > tv0){ tv4=tv3;ti4=ti3;tv3=tv2;ti3=ti2;tv2=tv1;ti2=ti1;tv1=tv0;ti1=ti0;tv0=(v);ti0=(ii);} \
    else if ((v) > tv1){ tv4=tv3;ti4=ti3;tv3=tv2;ti3=ti2;tv2=tv1;ti2=ti1;tv1=(v);ti1=(ii);} \
    else if ((v) > tv2){ tv4=tv3;ti4=ti3;tv3=tv2;ti3=ti2;tv2=(v);ti2=(ii);} \
    else if ((v) > tv3){ tv4=tv3;ti4=ti3;tv3=(v);ti3=(ii);} \
    else { tv4=(v);ti4=(ii);} \
  }

// merge partner lane's sorted top5 into mine (shuffles are unconditional)
#define TOP5_SHFL(off) { \
  float ov0=__shfl_xor(tv0,off), ov1=__shfl_xor(tv1,off), ov2=__shfl_xor(tv2,off), \
        ov3=__shfl_xor(tv3,off), ov4=__shfl_xor(tv4,off); \
  int   oi0=__shfl_xor(ti0,off), oi1=__shfl_xor(ti1,off), oi2=__shfl_xor(ti2,off), \
        oi3=__shfl_xor(ti3,off), oi4=__shfl_xor(ti4,off); \
  TOP5_INSERT(ov0,oi0) TOP5_INSERT(ov1,oi1) TOP5_INSERT(ov2,oi2) \
  TOP5_INSERT(ov3,oi3) TOP5_INSERT(ov4,oi4) }

// split one float into fp16 hi/lo pair (hi = RNE(x), lo = RNE(x - hi))
#define SPLITQ(H, L, slot, val) { \
  _Float16 _h = (_Float16)(val); \
  (H)[slot] = _h; \
  (L)[slot] = (_Float16)((val) - (float)_h); }

// ---------------- kernel 1: stats + changepoint + mode + encodings ----------------
__global__ __launch_bounds__(256) void k1_setup(
    const float* __restrict__ x,
    const float* __restrict__ cls_w, const float* __restrict__ cls_b,
    const float* __restrict__ prior_mean, const float* __restrict__ prior_var,
    const float* __restrict__ noise_var,
    const float* __restrict__ enc_W, const float* __restrict__ enc_b,
    const float* __restrict__ ln_g, const float* __restrict__ ln_b,
    float* __restrict__ q_ws, int* __restrict__ mode_ws)
{
  __shared__ float xl[TT*NCH];
  __shared__ float xf[TT];
  __shared__ float s1[TT+1];
  __shared__ float s2[TT+1];
  __shared__ float bfl[TT-32];
  __shared__ float xd[TT];
  __shared__ float rred[28*4];     // batched reduction scratch [stat][wave]
  int b = blockIdx.x, t = threadIdx.x;
  int lane = t & 63, wid = t >> 6;

  for (int i=t; i<TT*NCH; i+=256) xl[i] = x[(size_t)b*TT*NCH + i];
  __syncthreads();
  for (int i=t; i<TT; i+=256){
    float s=0.f;
    #pragma unroll
    for (int n=0;n<NCH;n++) s += xl[i*NCH+n];
    xf[i] = s*(1.0f/NCH);
  }
  __syncthreads();

  // ---- classifier feats: per-thread accumulate, wave-reduce, ONE barrier ----
  {
    float sum[NCH], ssq[NCH], mxa[NCH], mna[NCH];
    #pragma unroll
    for(int n=0;n<NCH;n++){ sum[n]=0.f; ssq[n]=0.f; mxa[n]=-INFINITY; mna[n]=INFINITY; }
    for (int i=t;i<TT;i+=256){
      #pragma unroll
      for(int n=0;n<NCH;n++){
        float v = xl[i*NCH+n];
        sum[n]+=v; ssq[n]+=v*v; mxa[n]=fmaxf(mxa[n],v); mna[n]=fminf(mna[n],v);
      }
    }
    #pragma unroll
    for(int n=0;n<NCH;n++){
      float sn  = wsum(sum[n]);
      float qn  = wsum(ssq[n]);
      float xn  = wmaxall(mxa[n]);
      float mn2 = wminall(mna[n]);
      if (lane==0){
        rred[(n*4+0)*4+wid]=sn;  rred[(n*4+1)*4+wid]=qn;
        rred[(n*4+2)*4+wid]=xn;  rred[(n*4+3)*4+wid]=mn2;
      }
    }
  }
  __syncthreads();
  float extreme_prob;
  {
    float f_mean=0.f, f_std=0.f, f_max=0.f, f_min=0.f;
    #pragma unroll
    for(int n=0;n<NCH;n++){
      const float* r0 = &rred[(n*4+0)*4];
      const float* r1 = &rred[(n*4+1)*4];
      const float* r2 = &rred[(n*4+2)*4];
      const float* r3 = &rred[(n*4+3)*4];
      float sn  = (r0[0]+r0[1])+(r0[2]+r0[3]);
      float qn  = (r1[0]+r1[1])+(r1[2]+r1[3]);
      float xn  = fmaxf(fmaxf(r2[0],r2[1]),fmaxf(r2[2],r2[3]));
      float mn2 = fminf(fminf(r3[0],r3[1]),fminf(r3[2],r3[3]));
      float m = sn*(1.0f/TT);
      float var = (qn - (float)TT*m*m)*(1.0f/(TT-1));
      f_mean += m; f_std += sqrtf(fmaxf(var, 0.f)); f_max += xn; f_min += mn2;
    }
    f_mean *= (1.0f/NCH); f_std *= (1.0f/NCH); f_max *= (1.0f/NCH); f_min *= (1.0f/NCH);
    f_std = fmaxf(f_std, 1e-6f);
    float trend = 0.f;
    #pragma unroll
    for(int n=0;n<NCH;n++) trend += (xl[(TT-1)*NCH+n]-xl[n]);
    trend *= (1.0f/NCH);
    float z = f_mean*cls_w[0]+f_std*cls_w[1]+f_max*cls_w[2]+f_min*cls_w[3]+trend*cls_w[4]+cls_b[0];
    extreme_prob = 1.f/(1.f+expf(-z));
  }

  // ---- parallel cumsum scan (s1: sum, s2: sumsq), 2 elems/thread ----
  {
    float a0 = xf[2*t], a1 = xf[2*t+1];
    float ps = a0+a1, qs = a0*a0 + a1*a1;
    xd[t] = ps; xd[256+t] = qs;
    __syncthreads();
    #pragma unroll
    for (int off=1; off<256; off<<=1){
      float pv=0.f, qv=0.f;
      if (t>=off){ pv = xd[t-off]; qv = xd[256+t-off]; }
      __syncthreads();
      xd[t] += pv; xd[256+t] += qv;
      __syncthreads();
    }
    float ip = xd[t], iq = xd[256+t];       // inclusive through pair t
    s1[2*t+1] = (ip-ps) + a0;  s2[2*t+1] = (iq-qs) + a0*a0;
    s1[2*t+2] = ip;            s2[2*t+2] = iq;
    if (t==0){ s1[0]=0.f; s2[0]=0.f; }
  }
  __syncthreads();

  // ---- Bayesian change point ----
  float pm = prior_mean[0];
  float pv = log1pf(expf(prior_var[0]));
  float nv = log1pf(expf(noise_var[0]));
  float sAll = s1[TT], qAll = s2[TT];
  float mw = sAll*(1.0f/TT);
  float vw = fmaxf((qAll - (float)TT*mw*mw)*(1.0f/(TT-1)), 1e-8f);
  float lmw = log_marg((float)TT, mw, vw, pm, pv, nv);
  for (int pp=16+t; pp<TT-16; pp+=256){
    float nl=(float)pp, nr=(float)(TT-pp);
    float ml=s1[pp]/nl;
    float vl=fmaxf((s2[pp]-nl*ml*ml)/(nl-1.f), 1e-8f);
    float sr=sAll-s1[pp], qr=qAll-s2[pp];
    float mr=sr/nr;
    float vr=fmaxf((qr-nr*mr*mr)/(nr-1.f), 1e-8f);
    bfl[pp-16] = log_marg(nl,ml,vl,pm,pv,nv)+log_marg(nr,mr,vr,pm,pv,nv)-lmw;
  }
  __syncthreads();
  float mv = -INFINITY;
  for (int i=t;i<TT-32;i+=256) mv = fmaxf(mv, bfl[i]);
  mv = wmaxall(mv);
  if (lane==0) rred[wid]=mv;
  __syncthreads();
  mv = fmaxf(fmaxf(rred[0],rred[1]),fmaxf(rred[2],rred[3]));
  float se=0.f, sme=0.f;
  for (int i=t;i<TT-32;i+=256){
    float e = expf(bfl[i]-mv);
    se += e;
    if (i+16 > 409) sme += e;   // pos > int(512*0.8)=409
  }
  se = wsum(se); sme = wsum(sme);
  if (lane==0){ rred[4+wid]=se; rred[8+wid]=sme; }
  __syncthreads();
  se  = (rred[4]+rred[5])+(rred[6]+rred[7]);
  sme = (rred[8]+rred[9])+(rred[10]+rred[11]);
  float near_end = (1.f/(1.f+expf(-mv))) * (sme/se);
  if (t==0) mode_ws[b] = (near_end>0.5f) ? 2 : ((extreme_prob>0.5f) ? 1 : 0);

  // ---- per-scale encodings (batched reductions) ----
  for (int si=0; si<SS; si++){
    int ds = 1<<si, Td = TT>>si;
    __syncthreads();
    for (int i=t;i<Td;i+=256)
      xd[i] = (si==0) ? xf[i] : (s1[(i+1)*ds]-s1[i*ds])*(1.0f/(float)ds);
    __syncthreads();
    float s=0.f, qq=0.f, mxv=-INFINITY, mnv=INFINITY;
    for (int i=t;i<Td;i+=256){ float v=xd[i]; s+=v; qq+=v*v; mxv=fmaxf(mxv,v); mnv=fminf(mnv,v); }
    s=wsum(s); qq=wsum(qq); mxv=wmaxall(mxv); mnv=wminall(mnv);
    if (lane==0){ rred[0*4+wid]=s; rred[1*4+wid]=qq; rred[2*4+wid]=mxv; rred[3*4+wid]=mnv; }
    __syncthreads();
    s   = (rred[0]+rred[1])+(rred[2]+rred[3]);
    qq  = (rred[4]+rred[5])+(rred[6]+rred[7]);
    mxv = fmaxf(fmaxf(rred[8],rred[9]),fmaxf(rred[10],rred[11]));
    mnv = fminf(fminf(rred[12],rred[13]),fminf(rred[14],rred[15]));
    float m  = s/(float)Td;
    float sd = fmaxf(sqrtf(fmaxf((qq-(float)Td*m*m)/((float)Td-1.f), 0.f)), 1e-6f);
    float tr = xd[Td-1]-xd[0];
    if (t < DD){
      float h = m*enc_W[0*DD+t] + sd*enc_W[1*DD+t] + mxv*enc_W[2*DD+t]
              + mnv*enc_W[3*DD+t] + tr*enc_W[4*DD+t] + enc_b[t];
      float mu  = wsum(h)*(1.0f/DD);
      float dv  = h-mu;
      float var = wsum(dv*dv)*(1.0f/DD);
      float hn  = dv*rsqrtf(var+1e-5f)*ln_g[t] + ln_b[t];
      float nrm2 = wsum(hn*hn);
      q_ws[(((size_t)si*BB)+b)*DD + t] = hn*rsqrtf(nrm2);
    }
  }
}

// ---------------- kernel 2: sims via split-fp16 MFMA, deferred register top5 ----------------
// r12 structure (19 KB LDS -> 8 blocks/CU possible) at NBLK=512: grid 2048,
// tiles/block 7->4, occupancy 4->up-to-8 blocks/CU. Same compulsory key
// traffic (each key read once). Single variable this round = parallelism.
__global__ __launch_bounds__(256) void k2_sims(
    const float* __restrict__ keys, const int* __restrict__ labels,
    const float* __restrict__ q_ws, const int* __restrict__ mode_ws,
    float* __restrict__ cand_val, int* __restrict__ cand_idx)
{
  __shared__ __align__(16) _Float16 khi[64*KLSH];
  __shared__ __align__(16) _Float16 klo[64*KLSH];
  __shared__ __align__(16) int lab[2][64];
  int bid = blockIdx.x;
  int s   = bid / NBLK, blk = bid % NBLK;
  int t = threadIdx.x, lane = t & 63;
  int w = __builtin_amdgcn_readfirstlane(t >> 6);   // wave id, provably uniform
  int k0   = blk*KPB;
  int kend = min(MM, k0+KPB);
  const float* kb  = keys + (size_t)s*MM*DD;
  const int*   lbb = labels + (size_t)s*MM;
  int cc_me  = w*16 + (lane&15);                    // my batch (MFMA D col)
  int mode_me = mode_ws[cc_me];

  // ---- B fragments (q, split-fp16) once per block: 16 VGPR total ----
  f16x8 bh0, bl0, bh1, bl1;
  {
    int kg = (lane>>4)*8;                      // k-group base
    const float* qg = q_ws + ((size_t)s*BB + cc_me)*DD + kg;
    float4 qa = *(const float4*)(qg);
    float4 qb = *(const float4*)(qg + 4);
    float4 qc = *(const float4*)(qg + 32);
    float4 qd = *(const float4*)(qg + 36);
    SPLITQ(bh0,bl0,0,qa.x) SPLITQ(bh0,bl0,1,qa.y) SPLITQ(bh0,bl0,2,qa.z) SPLITQ(bh0,bl0,3,qa.w)
    SPLITQ(bh0,bl0,4,qb.x) SPLITQ(bh0,bl0,5,qb.y) SPLITQ(bh0,bl0,6,qb.z) SPLITQ(bh0,bl0,7,qb.w)
    SPLITQ(bh1,bl1,0,qc.x) SPLITQ(bh1,bl1,1,qc.y) SPLITQ(bh1,bl1,2,qc.z) SPLITQ(bh1,bl1,3,qc.w)
    SPLITQ(bh1,bl1,4,qd.x) SPLITQ(bh1,bl1,5,qd.y) SPLITQ(bh1,bl1,6,qd.z) SPLITQ(bh1,bl1,7,qd.w)
  }

  float tv0=-INFINITY,tv1=-INFINITY,tv2=-INFINITY,tv3=-INFINITY,tv4=-INFINITY;
  int   ti0=0,ti1=0,ti2=0,ti3=0,ti4=0;

  float4 p0, p1, p2, p3;                       // in-flight staging regs
  int plab;
  #define ISSUE(c0n, cnn) { \
    const float* src = kb + (size_t)(c0n)*DD; \
    int lim = (cnn)*16; \
    if (t     < lim) p0 = *(const float4*)(src + (size_t)(t    )*4); \
    if (t+256 < lim) p1 = *(const float4*)(src + (size_t)(t+256)*4); \
    if (t+512 < lim) p2 = *(const float4*)(src + (size_t)(t+512)*4); \
    if (t+768 < lim) p3 = *(const float4*)(src + (size_t)(t+768)*4); \
    if (t < (cnn)) plab = lbb[(c0n)+t]; }
  #define CVTW(i, v) { \
    int _key=(i)>>4, _d0=((i)&15)*4; \
    _Float16 h0=(_Float16)(v).x, h1=(_Float16)(v).y, h2=(_Float16)(v).z, h3=(_Float16)(v).w; \
    _Float16 l0=(_Float16)((v).x-(float)h0), l1=(_Float16)((v).y-(float)h1), \
             l2=(_Float16)((v).z-(float)h2), l3=(_Float16)((v).w-(float)h3); \
    *(f16x4*)&khi[_key*KLSH + _d0] = (f16x4){h0,h1,h2,h3}; \
    *(f16x4*)&klo[_key*KLSH + _d0] = (f16x4){l0,l1,l2,l3}; }
  #define SWRITE(cnn, buf) { \
    int lim = (cnn)*16; \
    if (t     < lim) CVTW(t,     p0) \
    if (t+256 < lim) CVTW(t+256, p1) \
    if (t+512 < lim) CVTW(t+512, p2) \
    if (t+768 < lim) CVTW(t+768, p3) \
    if (t < (cnn)) lab[buf][t] = plab; }

  int nt = (kend - k0 + 63) >> 6;
  if (nt < 0) nt = 0;                          // guard tail blocks past MM
  ISSUE(k0, min(64, kend-k0));                 // prologue: tile 0 in flight

  int arow = lane & 15;                        // A row within 16-key subtile
  int kg   = (lane>>4)*8;                      // A k-group
  int drow = (lane>>4)*4;                      // key base within subtile (D rows)

  #define PHA(stv, CR) { \
    int rbase = ((stv)*16 + arow)*KLSH; \
    f16x8 ah0 = *(const f16x8*)&khi[rbase + kg]; \
    f16x8 al0 = *(const f16x8*)&klo[rbase + kg]; \
    f16x8 ah1 = *(const f16x8*)&khi[rbase + kg + 32]; \
    f16x8 al1 = *(const f16x8*)&klo[rbase + kg + 32]; \
    CR = __builtin_amdgcn_mfma_f32_16x16x32_f16(ah0, bh0, CR, 0, 0, 0); \
    CR = __builtin_amdgcn_mfma_f32_16x16x32_f16(al0, bh0, CR, 0, 0, 0); \
    CR = __builtin_amdgcn_mfma_f32_16x16x32_f16(ah0, bl0, CR, 0, 0, 0); \
    CR = __builtin_amdgcn_mfma_f32_16x16x32_f16(ah1, bh1, CR, 0, 0, 0); \
    CR = __builtin_amdgcn_mfma_f32_16x16x32_f16(al1, bh1, CR, 0, 0, 0); \
    CR = __builtin_amdgcn_mfma_f32_16x16x32_f16(ah1, bl1, CR, 0, 0, 0); }

  #define INS(stv, CR, buf) { \
    int kbase = (stv)*16 + drow; \
    int4 lb4 = *(const int4*)&lab[buf][kbase]; \
    { int rr=kbase+0; bool ok=(rr<cn)&((mode_me==0)|(lb4.x==mode_me)); \
      if(ok){ int gi=c0+rr; float v=CR[0]; TOP5_INSERT(v, gi) } } \
    { int rr=kbase+1; bool ok=(rr<cn)&((mode_me==0)|(lb4.y==mode_me)); \
      if(ok){ int gi=c0+rr; float v=CR[1]; TOP5_INSERT(v, gi) } } \
    { int rr=kbase+2; bool ok=(rr<cn)&((mode_me==0)|(lb4.z==mode_me)); \
      if(ok){ int gi=c0+rr; float v=CR[2]; TOP5_INSERT(v, gi) } } \
    { int rr=kbase+3; bool ok=(rr<cn)&((mode_me==0)|(lb4.w==mode_me)); \
      if(ok){ int gi=c0+rr; float v=CR[3]; TOP5_INSERT(v, gi) } } }

  for (int ti=0; ti<nt; ++ti){
    int c0 = k0 + (ti<<6);
    int cn = min(64, kend - c0);
    int buf = ti & 1;

    SWRITE(cn, buf);                           // vmcnt-drain + convert + ds_write
    if (ti+1 < nt)
      ISSUE(c0+64, min(64, kend-c0-64));       // next tile: loads fly over phase A
    __syncthreads();                           // B1: planes + labels ready

    // ---- phase A: pure split-fp16 MFMA into registers (no LDS stores) ----
    f32x4 cr0 = {0.f,0.f,0.f,0.f};
    f32x4 cr1 = {0.f,0.f,0.f,0.f};
    f32x4 cr2 = {0.f,0.f,0.f,0.f};
    f32x4 cr3 = {0.f,0.f,0.f,0.f};
    PHA(0, cr0)
    PHA(1, cr1)
    PHA(2, cr2)
    PHA(3, cr3)
    __syncthreads();                           // B2: all plane reads done

    // ---- deferred insert scan (r8's phase-B slot; registers + lab dbuf) ----
    INS(0, cr0, buf)
    INS(1, cr1, buf)
    INS(2, cr2, buf)
    INS(3, cr3, buf)
  }
  #undef ISSUE
  #undef CVTW
  #undef SWRITE
  #undef PHA
  #undef INS

  // merge the 4 lanes (g=0..3) holding batch cc_me: xor 16 then xor 32
  TOP5_SHFL(16)
  TOP5_SHFL(32)
  if (lane < 16){
    size_t o = (((size_t)s*NBLK + blk)*BB + (w*16+lane))*5;
    cand_val[o+0]=tv0; cand_val[o+1]=tv1; cand_val[o+2]=tv2; cand_val[o+3]=tv3; cand_val[o+4]=tv4;
    cand_idx[o+0]=ti0; cand_idx[o+1]=ti1; cand_idx[o+2]=ti2; cand_idx[o+3]=ti3; cand_idx[o+4]=ti4;
  }
}

// ---------------- kernel 3: merge candidates, softmax, gather values ----------------
// r8's structure; each of 256 threads pre-merges 2 cand-blocks (t, t+256)
// to cover NBLK=512, then the unchanged LDS tree.
__global__ __launch_bounds__(256) void k3_merge(
    const float* __restrict__ cand_val, const int* __restrict__ cand_idx,
    const float* __restrict__ values, const float* __restrict__ thresholds,
    float* __restrict__ top1_ws, float* __restrict__ retr_ws,
    float* __restrict__ out)
{
  __shared__ float lv[256*5];
  __shared__ int   li[256*5];
  __shared__ float wsm[5];
  __shared__ int   wix[5];
  int bid = blockIdx.x;
  int s = bid >> 6, b = bid & 63;
  int t = threadIdx.x;
  float tv0=-INFINITY,tv1=-INFINITY,tv2=-INFINITY,tv3=-INFINITY,tv4=-INFINITY;
  int   ti0=0,ti1=0,ti2=0,ti3=0,ti4=0;
  #pragma unroll
  for (int e=0;e<2;e++){
    size_t o = (((size_t)s*NBLK + (t + e*256))*BB + b)*5;
    #pragma unroll
    for (int j=0;j<5;j++){
      float v = cand_val[o+j]; int ii = cand_idx[o+j];
      TOP5_INSERT(v, ii)
    }
  }
  lv[t*5+0]=tv0; lv[t*5+1]=tv1; lv[t*5+2]=tv2; lv[t*5+3]=tv3; lv[t*5+4]=tv4;
  li[t*5+0]=ti0; li[t*5+1]=ti1; li[t*5+2]=ti2; li[t*5+3]=ti3; li[t*5+4]=ti4;
  __syncthreads();
  for (int stride=128; stride>=1; stride>>=1){
    if (t < stride){
      int p = t+stride;
      #pragma unroll
      for (int j=0;j<5;j++){
        float v = lv[p*5+j]; int ii = li[p*5+j];
        TOP5_INSERT(v, ii)
      }
      lv[t*5+0]=tv0; lv[t*5+1]=tv1; lv[t*5+2]=tv2; lv[t*5+3]=tv3; lv[t*5+4]=tv4;
      li[t*5+0]=ti0; li[t*5+1]=ti1; li[t*5+2]=ti2; li[t*5+3]=ti3; li[t*5+4]=ti4;
    }
    __syncthreads();
  }
  if (t==0){
    float e1=expf(tv1-tv0), e2=expf(tv2-tv0), e3=expf(tv3-tv0), e4=expf(tv4-tv0);
    float inv = 1.f/(1.f+e1+e2+e3+e4);
    wsm[0]=inv; wsm[1]=e1*inv; wsm[2]=e2*inv; wsm[3]=e3*inv; wsm[4]=e4*inv;
    wix[0]=ti0; wix[1]=ti1; wix[2]=ti2; wix[3]=ti3; wix[4]=ti4;
    top1_ws[s*BB+b] = tv0;
    out[(size_t)BB*PRED*NCH + b*SS + s] = 1.f/(1.f+expf(-(tv0-thresholds[s])));
  }
  __syncthreads();
  if (t < PRED){
    float acc=0.f;
    #pragma unroll
    for (int j=0;j<5;j++)
      acc += wsm[j]*values[((size_t)s*MM + wix[j])*PRED + t];
    retr_ws[((size_t)s*BB + b)*PRED + t] = acc;
  }
}

// ---------------- kernel 4: cross-scale fuse + broadcast over channels ----------------
__global__ __launch_bounds__(128) void k4_fuse(
    const float* __restrict__ top1_ws, const float* __restrict__ retr_ws,
    float* __restrict__ out)
{
  int b = blockIdx.x, t = threadIdx.x;
  float t0=top1_ws[b], t1=top1_ws[BB+b], t2=top1_ws[2*BB+b], t3=top1_ws[3*BB+b];
  float mx = fmaxf(fmaxf(t0,t1),fmaxf(t2,t3));
  float e0=expf(t0-mx), e1=expf(t1-mx), e2=expf(t2-mx), e3=expf(t3-mx);
  float inv = 1.f/(e0+e1+e2+e3);
  if (t < PRED){
    float f = (e0*retr_ws[((size_t)0*BB+b)*PRED+t] + e1*retr_ws[((size_t)1*BB+b)*PRED+t]
             + e2*retr_ws[((size_t)2*BB+b)*PRED+t] + e3*retr_ws[((size_t)3*BB+b)*PRED+t]) * inv;
    size_t base = ((size_t)b*PRED + t)*NCH;
    #pragma unroll
    for (int n=0;n<NCH;n++) out[base+n] = f;
  }
}

extern "C" void kernel_launch(void* const* d_in, const int* in_sizes, int n_in,
                              void* d_out, int out_size, void* d_ws, size_t ws_size,
                              hipStream_t stream)
{
  const float* x          = (const float*)d_in[0];
  const float* keys       = (const float*)d_in[1];
  const float* values     = (const float*)d_in[2];
  const int*   labels     = (const int*)  d_in[3];
  const float* thresholds = (const float*)d_in[4];
  const float* cls_w      = (const float*)d_in[5];
  const float* cls_b      = (const float*)d_in[6];
  const float* prior_mean = (const float*)d_in[7];
  const float* prior_var  = (const float*)d_in[8];
  const float* noise_var  = (const float*)d_in[9];
  const float* enc_W      = (const float*)d_in[10];
  const float* enc_b      = (const float*)d_in[11];
  const float* ln_g       = (const float*)d_in[12];
  const float* ln_b       = (const float*)d_in[13];
  float* out = (float*)d_out;

  float* q_ws     = (float*)d_ws;                                   // S*B*D
  int*   mode_ws  = (int*)(q_ws + (size_t)SS*BB*DD);                // B
  float* cand_val = (float*)(mode_ws + BB);                         // S*NBLK*B*5
  int*   cand_idx = (int*)(cand_val + (size_t)SS*NBLK*BB*5);        // S*NBLK*B*5
  float* top1_ws  = (float*)(cand_idx + (size_t)SS*NBLK*BB*5);      // S*B
  float* retr_ws  = top1_ws + SS*BB;                                // S*B*PRED

  k1_setup<<<dim3(BB), dim3(256), 0, stream>>>(x, cls_w, cls_b, prior_mean,
      prior_var, noise_var, enc_W, enc_b, ln_g, ln_b, q_ws, mode_ws);
  k2_sims<<<dim3(SS*NBLK), dim3(256), 0, stream>>>(keys, labels, q_ws, mode_ws,
      cand_val, cand_idx);
  k3_merge<<<dim3(SS*BB), dim3(256), 0, stream>>>(cand_val, cand_idx, values,
      thresholds, top1_ws, retr_ws, out);
  k4_fuse<<<dim3(BB), dim3(128), 0, stream>>>(top1_ws, retr_ws, out);
}

// Round 14
// 73.722 us; speedup vs baseline: 1.1583x; 1.1583x over previous
//
#include <hip/hip_runtime.h>
#include <math.h>

#define BB   64      // batch
#define TT   512     // time
#define NCH  7       // channels
#define SS   4       // scales
#define MM   100000  // memory entries
#define DD   64      // embed dim
#define PRED 96      // pred_len
#define NBLK 256     // k2 blocks per scale (measured optimum; 512 regressed -10us)
#define KPB  391     // ceil(MM/NBLK)
#define KLSH 72      // f16 plane row stride (shorts): 144B rows -> 16B-aligned b128 frags

typedef __attribute__((ext_vector_type(8))) _Float16 f16x8;
typedef __attribute__((ext_vector_type(4))) _Float16 f16x4;
typedef __attribute__((ext_vector_type(4))) float    f32x4;

// ---------------- wave reductions ----------------
__device__ __forceinline__ float wsum(float v){
  v += __shfl_xor(v,32); v += __shfl_xor(v,16); v += __shfl_xor(v,8);
  v += __shfl_xor(v,4);  v += __shfl_xor(v,2);  v += __shfl_xor(v,1);
  return v;
}
__device__ __forceinline__ float wmaxall(float v){
  v = fmaxf(v,__shfl_xor(v,32)); v = fmaxf(v,__shfl_xor(v,16));
  v = fmaxf(v,__shfl_xor(v,8));  v = fmaxf(v,__shfl_xor(v,4));
  v = fmaxf(v,__shfl_xor(v,2));  v = fmaxf(v,__shfl_xor(v,1));
  return v;
}
__device__ __forceinline__ float wminall(float v){
  v = fminf(v,__shfl_xor(v,32)); v = fminf(v,__shfl_xor(v,16));
  v = fminf(v,__shfl_xor(v,8));  v = fminf(v,__shfl_xor(v,4));
  v = fminf(v,__shfl_xor(v,2));  v = fminf(v,__shfl_xor(v,1));
  return v;
}

__device__ __forceinline__ float log_marg(float n, float mean, float var,
                                          float pm, float pv, float nv){
  float post_var = 1.f/(1.f/pv + n/nv);
  float post_mean = post_var*(pm/pv + n*mean/nv);
  return -0.5f*n*logf(6.283185307179586f*nv)
       + 0.5f*logf(post_var/pv)
       - 0.5f*(n*var/nv + mean*mean*n/nv - post_mean*post_mean/post_var + pm*pm/pv);
}

// sorted-desc top5 insert on registers tv0..tv4 / ti0..ti4
#define TOP5_INSERT(v, ii) \
  if ((v) > tv4) { \
    if ((v) > tv0){ tv4=tv3;ti4=ti3;tv3=tv2;ti3=ti2;tv2=tv1;ti2=ti1;tv1=tv0;ti1=ti0;tv0=(v);ti0=(ii);} \
    else if ((v) > tv1){ tv4=tv3;ti4=ti3;tv3=tv2;ti3=ti2;tv2=tv1;ti2=ti1;tv1=(v);ti1=(ii);} \
    else if ((v) > tv2){ tv4=tv3;ti4=ti3;tv3=tv2;ti3=ti2;tv2=(v);ti2=(ii);} \
    else if ((v) > tv3){ tv4=tv3;ti4=ti3;tv3=(v);ti3=(ii);} \
    else { tv4=(v);ti4=(ii);} \
  }

// split one float into fp16 hi/lo pair (hi = RNE(x), lo = RNE(x - hi))
#define SPLITQ(H, L, slot, val) { \
  _Float16 _h = (_Float16)(val); \
  (H)[slot] = _h; \
  (L)[slot] = (_Float16)((val) - (float)_h); }

// ---------------- kernel 1: stats + changepoint + mode + encodings ----------------
__global__ __launch_bounds__(256) void k1_setup(
    const float* __restrict__ x,
    const float* __restrict__ cls_w, const float* __restrict__ cls_b,
    const float* __restrict__ prior_mean, const float* __restrict__ prior_var,
    const float* __restrict__ noise_var,
    const float* __restrict__ enc_W, const float* __restrict__ enc_b,
    const float* __restrict__ ln_g, const float* __restrict__ ln_b,
    float* __restrict__ q_ws, int* __restrict__ mode_ws)
{
  __shared__ float xl[TT*NCH];
  __shared__ float xf[TT];
  __shared__ float s1[TT+1];
  __shared__ float s2[TT+1];
  __shared__ float bfl[TT-32];
  __shared__ float xd[TT];
  __shared__ float rred[28*4];     // batched reduction scratch [stat][wave]
  int b = blockIdx.x, t = threadIdx.x;
  int lane = t & 63, wid = t >> 6;

  for (int i=t; i<TT*NCH; i+=256) xl[i] = x[(size_t)b*TT*NCH + i];
  __syncthreads();
  for (int i=t; i<TT; i+=256){
    float s=0.f;
    #pragma unroll
    for (int n=0;n<NCH;n++) s += xl[i*NCH+n];
    xf[i] = s*(1.0f/NCH);
  }
  __syncthreads();

  // ---- classifier feats: per-thread accumulate, wave-reduce, ONE barrier ----
  {
    float sum[NCH], ssq[NCH], mxa[NCH], mna[NCH];
    #pragma unroll
    for(int n=0;n<NCH;n++){ sum[n]=0.f; ssq[n]=0.f; mxa[n]=-INFINITY; mna[n]=INFINITY; }
    for (int i=t;i<TT;i+=256){
      #pragma unroll
      for(int n=0;n<NCH;n++){
        float v = xl[i*NCH+n];
        sum[n]+=v; ssq[n]+=v*v; mxa[n]=fmaxf(mxa[n],v); mna[n]=fminf(mna[n],v);
      }
    }
    #pragma unroll
    for(int n=0;n<NCH;n++){
      float sn  = wsum(sum[n]);
      float qn  = wsum(ssq[n]);
      float xn  = wmaxall(mxa[n]);
      float mn2 = wminall(mna[n]);
      if (lane==0){
        rred[(n*4+0)*4+wid]=sn;  rred[(n*4+1)*4+wid]=qn;
        rred[(n*4+2)*4+wid]=xn;  rred[(n*4+3)*4+wid]=mn2;
      }
    }
  }
  __syncthreads();
  float extreme_prob;
  {
    float f_mean=0.f, f_std=0.f, f_max=0.f, f_min=0.f;
    #pragma unroll
    for(int n=0;n<NCH;n++){
      const float* r0 = &rred[(n*4+0)*4];
      const float* r1 = &rred[(n*4+1)*4];
      const float* r2 = &rred[(n*4+2)*4];
      const float* r3 = &rred[(n*4+3)*4];
      float sn  = (r0[0]+r0[1])+(r0[2]+r0[3]);
      float qn  = (r1[0]+r1[1])+(r1[2]+r1[3]);
      float xn  = fmaxf(fmaxf(r2[0],r2[1]),fmaxf(r2[2],r2[3]));
      float mn2 = fminf(fminf(r3[0],r3[1]),fminf(r3[2],r3[3]));
      float m = sn*(1.0f/TT);
      float var = (qn - (float)TT*m*m)*(1.0f/(TT-1));
      f_mean += m; f_std += sqrtf(fmaxf(var, 0.f)); f_max += xn; f_min += mn2;
    }
    f_mean *= (1.0f/NCH); f_std *= (1.0f/NCH); f_max *= (1.0f/NCH); f_min *= (1.0f/NCH);
    f_std = fmaxf(f_std, 1e-6f);
    float trend = 0.f;
    #pragma unroll
    for(int n=0;n<NCH;n++) trend += (xl[(TT-1)*NCH+n]-xl[n]);
    trend *= (1.0f/NCH);
    float z = f_mean*cls_w[0]+f_std*cls_w[1]+f_max*cls_w[2]+f_min*cls_w[3]+trend*cls_w[4]+cls_b[0];
    extreme_prob = 1.f/(1.f+expf(-z));
  }

  // ---- parallel cumsum scan (s1: sum, s2: sumsq), 2 elems/thread ----
  {
    float a0 = xf[2*t], a1 = xf[2*t+1];
    float ps = a0+a1, qs = a0*a0 + a1*a1;
    xd[t] = ps; xd[256+t] = qs;
    __syncthreads();
    #pragma unroll
    for (int off=1; off<256; off<<=1){
      float pv=0.f, qv=0.f;
      if (t>=off){ pv = xd[t-off]; qv = xd[256+t-off]; }
      __syncthreads();
      xd[t] += pv; xd[256+t] += qv;
      __syncthreads();
    }
    float ip = xd[t], iq = xd[256+t];       // inclusive through pair t
    s1[2*t+1] = (ip-ps) + a0;  s2[2*t+1] = (iq-qs) + a0*a0;
    s1[2*t+2] = ip;            s2[2*t+2] = iq;
    if (t==0){ s1[0]=0.f; s2[0]=0.f; }
  }
  __syncthreads();

  // ---- Bayesian change point ----
  float pm = prior_mean[0];
  float pv = log1pf(expf(prior_var[0]));
  float nv = log1pf(expf(noise_var[0]));
  float sAll = s1[TT], qAll = s2[TT];
  float mw = sAll*(1.0f/TT);
  float vw = fmaxf((qAll - (float)TT*mw*mw)*(1.0f/(TT-1)), 1e-8f);
  float lmw = log_marg((float)TT, mw, vw, pm, pv, nv);
  for (int pp=16+t; pp<TT-16; pp+=256){
    float nl=(float)pp, nr=(float)(TT-pp);
    float ml=s1[pp]/nl;
    float vl=fmaxf((s2[pp]-nl*ml*ml)/(nl-1.f), 1e-8f);
    float sr=sAll-s1[pp], qr=qAll-s2[pp];
    float mr=sr/nr;
    float vr=fmaxf((qr-nr*mr*mr)/(nr-1.f), 1e-8f);
    bfl[pp-16] = log_marg(nl,ml,vl,pm,pv,nv)+log_marg(nr,mr,vr,pm,pv,nv)-lmw;
  }
  __syncthreads();
  float mv = -INFINITY;
  for (int i=t;i<TT-32;i+=256) mv = fmaxf(mv, bfl[i]);
  mv = wmaxall(mv);
  if (lane==0) rred[wid]=mv;
  __syncthreads();
  mv = fmaxf(fmaxf(rred[0],rred[1]),fmaxf(rred[2],rred[3]));
  float se=0.f, sme=0.f;
  for (int i=t;i<TT-32;i+=256){
    float e = expf(bfl[i]-mv);
    se += e;
    if (i+16 > 409) sme += e;   // pos > int(512*0.8)=409
  }
  se = wsum(se); sme = wsum(sme);
  if (lane==0){ rred[4+wid]=se; rred[8+wid]=sme; }
  __syncthreads();
  se  = (rred[4]+rred[5])+(rred[6]+rred[7]);
  sme = (rred[8]+rred[9])+(rred[10]+rred[11]);
  float near_end = (1.f/(1.f+expf(-mv))) * (sme/se);
  if (t==0) mode_ws[b] = (near_end>0.5f) ? 2 : ((extreme_prob>0.5f) ? 1 : 0);

  // ---- per-scale encodings (batched reductions) ----
  for (int si=0; si<SS; si++){
    int ds = 1<<si, Td = TT>>si;
    __syncthreads();
    for (int i=t;i<Td;i+=256)
      xd[i] = (si==0) ? xf[i] : (s1[(i+1)*ds]-s1[i*ds])*(1.0f/(float)ds);
    __syncthreads();
    float s=0.f, qq=0.f, mxv=-INFINITY, mnv=INFINITY;
    for (int i=t;i<Td;i+=256){ float v=xd[i]; s+=v; qq+=v*v; mxv=fmaxf(mxv,v); mnv=fminf(mnv,v); }
    s=wsum(s); qq=wsum(qq); mxv=wmaxall(mxv); mnv=wminall(mnv);
    if (lane==0){ rred[0*4+wid]=s; rred[1*4+wid]=qq; rred[2*4+wid]=mxv; rred[3*4+wid]=mnv; }
    __syncthreads();
    s   = (rred[0]+rred[1])+(rred[2]+rred[3]);
    qq  = (rred[4]+rred[5])+(rred[6]+rred[7]);
    mxv = fmaxf(fmaxf(rred[8],rred[9]),fmaxf(rred[10],rred[11]));
    mnv = fminf(fminf(rred[12],rred[13]),fminf(rred[14],rred[15]));
    float m  = s/(float)Td;
    float sd = fmaxf(sqrtf(fmaxf((qq-(float)Td*m*m)/((float)Td-1.f), 0.f)), 1e-6f);
    float tr = xd[Td-1]-xd[0];
    if (t < DD){
      float h = m*enc_W[0*DD+t] + sd*enc_W[1*DD+t] + mxv*enc_W[2*DD+t]
              + mnv*enc_W[3*DD+t] + tr*enc_W[4*DD+t] + enc_b[t];
      float mu  = wsum(h)*(1.0f/DD);
      float dv  = h-mu;
      float var = wsum(dv*dv)*(1.0f/DD);
      float hn  = dv*rsqrtf(var+1e-5f)*ln_g[t] + ln_b[t];
      float nrm2 = wsum(hn*hn);
      q_ws[(((size_t)si*BB)+b)*DD + t] = hn*rsqrtf(nrm2);
    }
  }
}

// ---------------- kernel 2: sims via split-fp16 MFMA + per-block top5 ----------------
// r8 exact (measured best 73.5us): pure MFMA phase between barriers, top-5
// scan in separate phase B overlapping other waves' MFMA; T14 async-STAGE.
__global__ __launch_bounds__(256) void k2_sims(
    const float* __restrict__ keys, const int* __restrict__ labels,
    const float* __restrict__ q_ws, const int* __restrict__ mode_ws,
    float* __restrict__ cand_val, int* __restrict__ cand_idx)
{
  __shared__ __align__(16) _Float16 khi[64*KLSH];
  __shared__ __align__(16) _Float16 klo[64*KLSH];
  __shared__ float sims[64*65];    // [key][batch], stride 65 (2-way alias = free)
  int bid = blockIdx.x;
  int s   = bid / NBLK, blk = bid % NBLK;
  int t = threadIdx.x, lane = t & 63;
  int w = __builtin_amdgcn_readfirstlane(t >> 6);   // wave id, provably uniform
  int k0   = blk*KPB;
  int kend = min(MM, k0+KPB);
  int mode_l = mode_ws[lane];                        // lane = batch in phase B
  const float* kb  = keys + (size_t)s*MM*DD;
  const int*   lbb = labels + (size_t)s*MM;

  // ---- B fragments (q, split-fp16) once per block: 16 VGPR total ----
  f16x8 bh0, bl0, bh1, bl1;
  {
    int bb = w*16 + (lane&15);                 // batch (MFMA col)
    int kg = (lane>>4)*8;                      // k-group base
    const float* qg = q_ws + ((size_t)s*BB + bb)*DD + kg;
    float4 qa = *(const float4*)(qg);
    float4 qb = *(const float4*)(qg + 4);
    float4 qc = *(const float4*)(qg + 32);
    float4 qd = *(const float4*)(qg + 36);
    SPLITQ(bh0,bl0,0,qa.x) SPLITQ(bh0,bl0,1,qa.y) SPLITQ(bh0,bl0,2,qa.z) SPLITQ(bh0,bl0,3,qa.w)
    SPLITQ(bh0,bl0,4,qb.x) SPLITQ(bh0,bl0,5,qb.y) SPLITQ(bh0,bl0,6,qb.z) SPLITQ(bh0,bl0,7,qb.w)
    SPLITQ(bh1,bl1,0,qc.x) SPLITQ(bh1,bl1,1,qc.y) SPLITQ(bh1,bl1,2,qc.z) SPLITQ(bh1,bl1,3,qc.w)
    SPLITQ(bh1,bl1,4,qd.x) SPLITQ(bh1,bl1,5,qd.y) SPLITQ(bh1,bl1,6,qd.z) SPLITQ(bh1,bl1,7,qd.w)
  }

  float tv0=-INFINITY,tv1=-INFINITY,tv2=-INFINITY,tv3=-INFINITY,tv4=-INFINITY;
  int   ti0=0,ti1=0,ti2=0,ti3=0,ti4=0;

  float4 p0, p1, p2, p3;                       // in-flight staging regs
  #define ISSUE(c0n, cnn) { \
    const float* src = kb + (size_t)(c0n)*DD; \
    int lim = (cnn)*16; \
    if (t     < lim) p0 = *(const float4*)(src + (size_t)(t    )*4); \
    if (t+256 < lim) p1 = *(const float4*)(src + (size_t)(t+256)*4); \
    if (t+512 < lim) p2 = *(const float4*)(src + (size_t)(t+512)*4); \
    if (t+768 < lim) p3 = *(const float4*)(src + (size_t)(t+768)*4); }
  #define CVTW(i, v) { \
    int _key=(i)>>4, _d0=((i)&15)*4; \
    _Float16 h0=(_Float16)(v).x, h1=(_Float16)(v).y, h2=(_Float16)(v).z, h3=(_Float16)(v).w; \
    _Float16 l0=(_Float16)((v).x-(float)h0), l1=(_Float16)((v).y-(float)h1), \
             l2=(_Float16)((v).z-(float)h2), l3=(_Float16)((v).w-(float)h3); \
    *(f16x4*)&khi[_key*KLSH + _d0] = (f16x4){h0,h1,h2,h3}; \
    *(f16x4*)&klo[_key*KLSH + _d0] = (f16x4){l0,l1,l2,l3}; }
  #define SWRITE(cnn) { \
    int lim = (cnn)*16; \
    if (t     < lim) CVTW(t,     p0) \
    if (t+256 < lim) CVTW(t+256, p1) \
    if (t+512 < lim) CVTW(t+512, p2) \
    if (t+768 < lim) CVTW(t+768, p3) }

  int nt = (kend - k0 + 63) >> 6;
  ISSUE(k0, min(64, kend-k0));                 // prologue: tile 0 in flight

  for (int ti=0; ti<nt; ++ti){
    int c0 = k0 + (ti<<6);
    int cn = min(64, kend - c0);

    SWRITE(cn);                                // vmcnt-drain + convert + ds_write
    if (ti+1 < nt)
      ISSUE(c0+64, min(64, kend-c0-64));       // next tile: loads fly over phase A+B
    __syncthreads();                           // B1: planes ready

    // ---- phase A: split-fp16 MFMA (stale tail rows unread) ----
    {
      int arow = lane & 15;                    // A row within 16-key subtile
      int kg   = (lane>>4)*8;                  // A k-group
      int cc   = w*16 + (lane&15);             // D col = batch
      int drow = (lane>>4)*4;                  // D row base within subtile
      #pragma unroll
      for (int st=0; st<4; ++st){
        int rbase = (st*16 + arow)*KLSH;
        f16x8 ah0 = *(const f16x8*)&khi[rbase + kg];
        f16x8 al0 = *(const f16x8*)&klo[rbase + kg];
        f16x8 ah1 = *(const f16x8*)&khi[rbase + kg + 32];
        f16x8 al1 = *(const f16x8*)&klo[rbase + kg + 32];
        f32x4 c = {0.f, 0.f, 0.f, 0.f};
        c = __builtin_amdgcn_mfma_f32_16x16x32_f16(ah0, bh0, c, 0, 0, 0);
        c = __builtin_amdgcn_mfma_f32_16x16x32_f16(al0, bh0, c, 0, 0, 0);
        c = __builtin_amdgcn_mfma_f32_16x16x32_f16(ah0, bl0, c, 0, 0, 0);
        c = __builtin_amdgcn_mfma_f32_16x16x32_f16(ah1, bh1, c, 0, 0, 0);
        c = __builtin_amdgcn_mfma_f32_16x16x32_f16(al1, bh1, c, 0, 0, 0);
        c = __builtin_amdgcn_mfma_f32_16x16x32_f16(ah1, bl1, c, 0, 0, 0);
        int r0 = st*16 + drow;
        sims[(r0+0)*65 + cc] = c[0];
        sims[(r0+1)*65 + cc] = c[1];
        sims[(r0+2)*65 + cc] = c[2];
        sims[(r0+3)*65 + cc] = c[3];
      }
    }
    __syncthreads();                           // B2: sims ready + plane reads done

    // ---- phase B: lane = batch; each wave scans its 16-key slice ----
    {
      int mlo = w*16, mhi = min(cn, w*16+16);
      for (int m=mlo; m<mhi; m++){
        int lb = lbb[c0+m];                    // wave-uniform -> s_load
        float v = sims[m*65+lane];
        bool allowed = (mode_l==0) | (lb==mode_l);
        if (allowed){
          int gidx = c0+m;
          TOP5_INSERT(v, gidx)
        }
      }
    }
    // next iteration's SWRITE touches planes only (not sims); B1 orders sims.
  }
  #undef ISSUE
  #undef CVTW
  #undef SWRITE

  __syncthreads();
  // merge 4 wave-lists per batch -> per-block sorted top5
  float* mvp = sims;       // reuse
  int*   mip = (int*)khi;  // reuse (9216B >= 5120B)
  int slot = (w*64+lane)*5;
  mvp[slot+0]=tv0; mvp[slot+1]=tv1; mvp[slot+2]=tv2; mvp[slot+3]=tv3; mvp[slot+4]=tv4;
  mip[slot+0]=ti0; mip[slot+1]=ti1; mip[slot+2]=ti2; mip[slot+3]=ti3; mip[slot+4]=ti4;
  __syncthreads();
  if (t < 64){
    float tv0=mvp[t*5+0], tv1=mvp[t*5+1], tv2=mvp[t*5+2], tv3=mvp[t*5+3], tv4=mvp[t*5+4];
    int   ti0=mip[t*5+0], ti1=mip[t*5+1], ti2=mip[t*5+2], ti3=mip[t*5+3], ti4=mip[t*5+4];
    #pragma unroll
    for (int ww=1; ww<4; ww++){
      #pragma unroll
      for (int j=0;j<5;j++){
        float v = mvp[(ww*64+t)*5+j]; int ii = mip[(ww*64+t)*5+j];
        TOP5_INSERT(v, ii)
      }
    }
    size_t o = (((size_t)s*NBLK + blk)*BB + t)*5;
    cand_val[o+0]=tv0; cand_val[o+1]=tv1; cand_val[o+2]=tv2; cand_val[o+3]=tv3; cand_val[o+4]=tv4;
    cand_idx[o+0]=ti0; cand_idx[o+1]=ti1; cand_idx[o+2]=ti2; cand_idx[o+3]=ti3; cand_idx[o+4]=ti4;
  }
}

// ---------------- kernel 3: merge candidates, softmax, gather values ----------------
__global__ __launch_bounds__(256) void k3_merge(
    const float* __restrict__ cand_val, const int* __restrict__ cand_idx,
    const float* __restrict__ values, const float* __restrict__ thresholds,
    float* __restrict__ top1_ws, float* __restrict__ retr_ws,
    float* __restrict__ out)
{
  __shared__ float lv[NBLK*5];
  __shared__ int   li[NBLK*5];
  __shared__ float wsm[5];
  __shared__ int   wix[5];
  int bid = blockIdx.x;
  int s = bid >> 6, b = bid & 63;
  int t = threadIdx.x;
  size_t o = (((size_t)s*NBLK + t)*BB + b)*5;
  float tv0=cand_val[o+0], tv1=cand_val[o+1], tv2=cand_val[o+2], tv3=cand_val[o+3], tv4=cand_val[o+4];
  int   ti0=cand_idx[o+0], ti1=cand_idx[o+1], ti2=cand_idx[o+2], ti3=cand_idx[o+3], ti4=cand_idx[o+4];
  lv[t*5+0]=tv0; lv[t*5+1]=tv1; lv[t*5+2]=tv2; lv[t*5+3]=tv3; lv[t*5+4]=tv4;
  li[t*5+0]=ti0; li[t*5+1]=ti1; li[t*5+2]=ti2; li[t*5+3]=ti3; li[t*5+4]=ti4;
  __syncthreads();
  for (int stride=128; stride>=1; stride>>=1){
    if (t < stride){
      int p = t+stride;
      #pragma unroll
      for (int j=0;j<5;j++){
        float v = lv[p*5+j]; int ii = li[p*5+j];
        TOP5_INSERT(v, ii)
      }
      lv[t*5+0]=tv0; lv[t*5+1]=tv1; lv[t*5+2]=tv2; lv[t*5+3]=tv3; lv[t*5+4]=tv4;
      li[t*5+0]=ti0; li[t*5+1]=ti1; li[t*5+2]=ti2; li[t*5+3]=ti3; li[t*5+4]=ti4;
    }
    __syncthreads();
  }
  if (t==0){
    float e1=expf(tv1-tv0), e2=expf(tv2-tv0), e3=expf(tv3-tv0), e4=expf(tv4-tv0);
    float inv = 1.f/(1.f+e1+e2+e3+e4);
    wsm[0]=inv; wsm[1]=e1*inv; wsm[2]=e2*inv; wsm[3]=e3*inv; wsm[4]=e4*inv;
    wix[0]=ti0; wix[1]=ti1; wix[2]=ti2; wix[3]=ti3; wix[4]=ti4;
    top1_ws[s*BB+b] = tv0;
    out[(size_t)BB*PRED*NCH + b*SS + s] = 1.f/(1.f+expf(-(tv0-thresholds[s])));
  }
  __syncthreads();
  if (t < PRED){
    float acc=0.f;
    #pragma unroll
    for (int j=0;j<5;j++)
      acc += wsm[j]*values[((size_t)s*MM + wix[j])*PRED + t];
    retr_ws[((size_t)s*BB + b)*PRED + t] = acc;
  }
}

// ---------------- kernel 4: cross-scale fuse + broadcast over channels ----------------
__global__ __launch_bounds__(128) void k4_fuse(
    const float* __restrict__ top1_ws, const float* __restrict__ retr_ws,
    float* __restrict__ out)
{
  int b = blockIdx.x, t = threadIdx.x;
  float t0=top1_ws[b], t1=top1_ws[BB+b], t2=top1_ws[2*BB+b], t3=top1_ws[3*BB+b];
  float mx = fmaxf(fmaxf(t0,t1),fmaxf(t2,t3));
  float e0=expf(t0-mx), e1=expf(t1-mx), e2=expf(t2-mx), e3=expf(t3-mx);
  float inv = 1.f/(e0+e1+e2+e3);
  if (t < PRED){
    float f = (e0*retr_ws[((size_t)0*BB+b)*PRED+t] + e1*retr_ws[((size_t)1*BB+b)*PRED+t]
             + e2*retr_ws[((size_t)2*BB+b)*PRED+t] + e3*retr_ws[((size_t)3*BB+b)*PRED+t]) * inv;
    size_t base = ((size_t)b*PRED + t)*NCH;
    #pragma unroll
    for (int n=0;n<NCH;n++) out[base+n] = f;
  }
}

extern "C" void kernel_launch(void* const* d_in, const int* in_sizes, int n_in,
                              void* d_out, int out_size, void* d_ws, size_t ws_size,
                              hipStream_t stream)
{
  const float* x          = (const float*)d_in[0];
  const float* keys       = (const float*)d_in[1];
  const float* values     = (const float*)d_in[2];
  const int*   labels     = (const int*)  d_in[3];
  const float* thresholds = (const float*)d_in[4];
  const float* cls_w      = (const float*)d_in[5];
  const float* cls_b      = (const float*)d_in[6];
  const float* prior_mean = (const float*)d_in[7];
  const float* prior_var  = (const float*)d_in[8];
  const float* noise_var  = (const float*)d_in[9];
  const float* enc_W      = (const float*)d_in[10];
  const float* enc_b      = (const float*)d_in[11];
  const float* ln_g       = (const float*)d_in[12];
  const float* ln_b       = (const float*)d_in[13];
  float* out = (float*)d_out;

  float* q_ws     = (float*)d_ws;                                   // S*B*D
  int*   mode_ws  = (int*)(q_ws + (size_t)SS*BB*DD);                // B
  float* cand_val = (float*)(mode_ws + BB);                         // S*NBLK*B*5
  int*   cand_idx = (int*)(cand_val + (size_t)SS*NBLK*BB*5);        // S*NBLK*B*5
  float* top1_ws  = (float*)(cand_idx + (size_t)SS*NBLK*BB*5);      // S*B
  float* retr_ws  = top1_ws + SS*BB;                                // S*B*PRED

  k1_setup<<<dim3(BB), dim3(256), 0, stream>>>(x, cls_w, cls_b, prior_mean,
      prior_var, noise_var, enc_W, enc_b, ln_g, ln_b, q_ws, mode_ws);
  k2_sims<<<dim3(SS*NBLK), dim3(256), 0, stream>>>(keys, labels, q_ws, mode_ws,
      cand_val, cand_idx);
  k3_merge<<<dim3(SS*BB), dim3(256), 0, stream>>>(cand_val, cand_idx, values,
      thresholds, top1_ws, retr_ws, out);
  k4_fuse<<<dim3(BB), dim3(128), 0, stream>>>(top1_ws, retr_ws, out);
}